// Round 1
// baseline (1538.117 us; speedup 1.0000x reference)
//
#include <hip/hip_runtime.h>

// LSTM (H=32) over padded batch B=2048, T=1024 + masked mean pool + sigmoid cls.
// Strategy: one wave (64 lanes) per batch element. Lane j owns gate rows j and
// j+64 of the fused [4H=128 x H=32] matvec; all 4 weight rows (128 fp32) held
// in registers. h broadcast via v_readlane (constant lane idx after unroll);
// x_t loads are wave-uniform -> scalar loads. Prefix-mask early exit at L.

__device__ __forceinline__ float fast_sigmoid(float x) {
    return 1.0f / (1.0f + __expf(-x));   // x=-inf path: 1/(1+inf)=0, no NaN
}
__device__ __forceinline__ float fast_tanh(float x) {
    return 2.0f * fast_sigmoid(2.0f * x) - 1.0f;
}

__device__ __forceinline__ float lane_bcast(float v, int srclane) {
    return __int_as_float(__builtin_amdgcn_readlane(__float_as_int(v), srclane));
}

__global__ __launch_bounds__(64)
void lstm_fused_kernel(const float* __restrict__ x,      // [B,T,32]
                       const float* __restrict__ mask,   // [B,T]
                       const float* __restrict__ w_ih,   // [128,32]
                       const float* __restrict__ w_hh,   // [128,32]
                       const float* __restrict__ b_ih,   // [128]
                       const float* __restrict__ b_hh,   // [128]
                       const float* __restrict__ w_cls,  // [1,32]
                       const float* __restrict__ b_cls,  // [1]
                       float* __restrict__ out,          // pooled [B,32] ++ probs [B]
                       int B, int T)
{
    const int b = blockIdx.x;
    if (b >= B) return;
    const int lane = threadIdx.x;        // 0..63
    const int rowA = lane;               // rows 0..63  : i (k<32) / f (k>=32)
    const int rowB = lane + 64;          // rows 64..127: g (k<32) / o (k>=32)

    // ---- weights for my two rows into registers (4 x 32 = 128 VGPRs) ----
    float wiA[32], whA[32], wiB[32], whB[32];
#pragma unroll
    for (int m = 0; m < 32; ++m) {
        wiA[m] = w_ih[rowA * 32 + m];
        whA[m] = w_hh[rowA * 32 + m];
        wiB[m] = w_ih[rowB * 32 + m];
        whB[m] = w_hh[rowB * 32 + m];
    }
    const float bA = b_ih[rowA] + b_hh[rowA];
    const float bB = b_ih[rowB] + b_hh[rowB];

    // ---- sequence length L = sum(mask[b,:]) (prefix mask by construction) ----
    const float* mrow = mask + (size_t)b * T;
    float msum = 0.0f;
    for (int t = lane; t < T; t += 64) msum += mrow[t];
#pragma unroll
    for (int off = 32; off > 0; off >>= 1)
        msum += __shfl_down(msum, off, 64);
    const float Lf = __shfl(msum, 0, 64);     // total in lane 0, broadcast
    const int L = (int)(Lf + 0.5f);           // lengths in [1, T]

    // ---- recurrence ----
    // lane k<32 carries h[k], c[k]; lanes >=32 carry don't-care mirrors.
    float h = 0.0f, c = 0.0f, hsum = 0.0f;
    const float* xb = x + (size_t)b * T * 32;

    for (int t = 0; t < L; ++t) {
        const float* xt = xb + t * 32;        // wave-uniform -> scalar loads
        float aAx = bA, aAh = 0.0f, aBx = bB, aBh = 0.0f;
#pragma unroll
        for (int m = 0; m < 32; ++m) {
            const float xm = xt[m];
            const float hm = lane_bcast(h, m);
            aAx = fmaf(xm, wiA[m], aAx);
            aAh = fmaf(hm, whA[m], aAh);
            aBx = fmaf(xm, wiB[m], aBx);
            aBh = fmaf(hm, whB[m], aBh);
        }
        const float accA = aAx + aAh;   // lane k<32: i_pre[k]; k>=32: f_pre[k-32]
        const float accB = aBx + aBh;   // lane k<32: g_pre[k]; k>=32: o_pre[k-32]
        const float accA2 = __shfl_xor(accA, 32, 64);  // partner's preact
        const float accB2 = __shfl_xor(accB, 32, 64);
        // valid for lanes k<32 (lanes>=32 compute bounded garbage, never read)
        const float ig = fast_sigmoid(accA);
        const float fg = fast_sigmoid(accA2);
        const float gg = fast_tanh(accB);
        const float og = fast_sigmoid(accB2);
        c = fg * c + ig * gg;
        h = og * fast_tanh(c);
        hsum += h;
    }

    // ---- masked mean pool + write pooled ----
    const float pooled = hsum / Lf;           // Lf >= 1 always
    if (lane < 32) out[(size_t)b * 32 + lane] = pooled;

    // ---- classifier: sigmoid(pooled . w_cls + b_cls) ----
    float contrib = (lane < 32) ? pooled * w_cls[lane] : 0.0f;
#pragma unroll
    for (int off = 32; off > 0; off >>= 1)
        contrib += __shfl_down(contrib, off, 64);
    if (lane == 0)
        out[(size_t)B * 32 + b] = fast_sigmoid(contrib + b_cls[0]);
}

extern "C" void kernel_launch(void* const* d_in, const int* in_sizes, int n_in,
                              void* d_out, int out_size, void* d_ws, size_t ws_size,
                              hipStream_t stream)
{
    const float* x     = (const float*)d_in[0];
    const float* mask  = (const float*)d_in[1];
    const float* w_ih  = (const float*)d_in[2];
    const float* w_hh  = (const float*)d_in[3];
    const float* b_ih  = (const float*)d_in[4];
    const float* b_hh  = (const float*)d_in[5];
    const float* w_cls = (const float*)d_in[6];
    const float* b_cls = (const float*)d_in[7];
    float* out = (float*)d_out;

    const int B = out_size / 33;        // pooled B*32 + probs B
    const int T = in_sizes[1] / B;      // mask is [B,T]

    lstm_fused_kernel<<<B, 64, 0, stream>>>(x, mask, w_ih, w_hh, b_ih, b_hh,
                                            w_cls, b_cls, out, B, T);
}

// Round 2
// 962.976 us; speedup vs baseline: 1.5973x; 1.5973x over previous
//
#include <hip/hip_runtime.h>

// LSTM (H=32), B=2048, T=1024, prefix-masked + mean pool + sigmoid cls.
// One wave per batch element. Lane j owns gate rows j and j+64 (i/f/g/o fused
// 128x32 matvec). Weights pinned in VGPRs via opaque asm. x is read with
// per-lane coalesced vector loads prefetched 4 steps ahead (one 256B wave-load
// covers 2 timesteps), broadcast at use via v_readlane (const lane index).

#define PIN(v) asm volatile("" : "+v"(v))

__device__ __forceinline__ float fast_sigmoid(float x) {
    return __builtin_amdgcn_rcpf(1.0f + __expf(-x));
}
__device__ __forceinline__ float fast_tanh(float x) {
    return fmaf(2.0f, fast_sigmoid(2.0f * x), -1.0f);
}
__device__ __forceinline__ float lane_bcast(float v, int srclane) {
    return __int_as_float(__builtin_amdgcn_readlane(__float_as_int(v), srclane));
}
__device__ __forceinline__ float get(const float4& v, int c) {
    return c == 0 ? v.x : c == 1 ? v.y : c == 2 ? v.z : v.w;
}

__device__ __forceinline__ void lstm_step(
    float xv, int half,
    const float4* wiA, const float4* whA, const float4* wiB, const float4* whB,
    float bA, float bB, float& h, float& c, float& hsum)
{
    // 8 independent FMA chains of depth 16 (shorter critical path for tail).
    float aA0 = bA,  aA1 = 0.f, aA2 = 0.f, aA3 = 0.f;
    float aB0 = bB,  aB1 = 0.f, aB2 = 0.f, aB3 = 0.f;
#pragma unroll
    for (int m = 0; m < 16; ++m) {
        const float xm = lane_bcast(xv, half * 32 + m);
        const float hm = lane_bcast(h, m);
        aA0 = fmaf(xm, get(wiA[m >> 2], m & 3), aA0);
        aA1 = fmaf(hm, get(whA[m >> 2], m & 3), aA1);
        aB0 = fmaf(xm, get(wiB[m >> 2], m & 3), aB0);
        aB1 = fmaf(hm, get(whB[m >> 2], m & 3), aB1);
    }
#pragma unroll
    for (int m = 16; m < 32; ++m) {
        const float xm = lane_bcast(xv, half * 32 + m);
        const float hm = lane_bcast(h, m);
        aA2 = fmaf(xm, get(wiA[m >> 2], m & 3), aA2);
        aA3 = fmaf(hm, get(whA[m >> 2], m & 3), aA3);
        aB2 = fmaf(xm, get(wiB[m >> 2], m & 3), aB2);
        aB3 = fmaf(hm, get(whB[m >> 2], m & 3), aB3);
    }
    const float accA  = (aA0 + aA1) + (aA2 + aA3);  // i_pre (k<32) / f_pre (k>=32)
    const float accB  = (aB0 + aB1) + (aB2 + aB3);  // g_pre (k<32) / o_pre (k>=32)
    const float accA2 = __shfl_xor(accA, 32, 64);
    const float accB2 = __shfl_xor(accB, 32, 64);
    const float ig = fast_sigmoid(accA);
    const float fg = fast_sigmoid(accA2);
    const float gg = fast_tanh(accB);
    const float og = fast_sigmoid(accB2);
    c = fg * c + ig * gg;            // lanes >=32: bounded garbage, never read
    h = og * fast_tanh(c);
    hsum += h;
}

__global__ __launch_bounds__(64, 2)
void lstm_fused_kernel(const float* __restrict__ x,      // [B,T,32]
                       const float* __restrict__ mask,   // [B,T]
                       const float* __restrict__ w_ih,   // [128,32]
                       const float* __restrict__ w_hh,   // [128,32]
                       const float* __restrict__ b_ih,   // [128]
                       const float* __restrict__ b_hh,   // [128]
                       const float* __restrict__ w_cls,  // [1,32]
                       const float* __restrict__ b_cls,  // [1]
                       float* __restrict__ out,          // pooled [B,32] ++ probs [B]
                       int B, int T)
{
    const int b = blockIdx.x;
    if (b >= B) return;
    const int lane = threadIdx.x;
    const int rowA = lane;          // rows 0..63  : i (k<32) / f (k>=32)
    const int rowB = lane + 64;     // rows 64..127: g (k<32) / o (k>=32)

    // ---- weights into registers (4 x 8 float4 = 128 VGPRs), pinned ----
    const float4* wi4 = (const float4*)w_ih;
    const float4* wh4 = (const float4*)w_hh;
    float4 wiA[8], whA[8], wiB[8], whB[8];
#pragma unroll
    for (int q = 0; q < 8; ++q) {
        wiA[q] = wi4[rowA * 8 + q];
        whA[q] = wh4[rowA * 8 + q];
        wiB[q] = wi4[rowB * 8 + q];
        whB[q] = wh4[rowB * 8 + q];
    }
#pragma unroll
    for (int q = 0; q < 8; ++q) {
        PIN(wiA[q].x); PIN(wiA[q].y); PIN(wiA[q].z); PIN(wiA[q].w);
        PIN(whA[q].x); PIN(whA[q].y); PIN(whA[q].z); PIN(whA[q].w);
        PIN(wiB[q].x); PIN(wiB[q].y); PIN(wiB[q].z); PIN(wiB[q].w);
        PIN(whB[q].x); PIN(whB[q].y); PIN(whB[q].z); PIN(whB[q].w);
    }
    const float bA = b_ih[rowA] + b_hh[rowA];
    const float bB = b_ih[rowB] + b_hh[rowB];

    // ---- L = sum(mask[b,:]) (prefix mask) ----
    const float* mrow = mask + (size_t)b * T;
    float msum = 0.0f;
    for (int t = lane; t < T; t += 64) msum += mrow[t];
#pragma unroll
    for (int off = 32; off > 0; off >>= 1) msum += __shfl_down(msum, off, 64);
    const float Lf = __shfl(msum, 0, 64);
    const int L = (int)(Lf + 0.5f);

    // ---- recurrence with 4-step-lookahead x prefetch ----
    // pair p covers steps (2p, 2p+1); xv register: lane l = xb[p*64 + l],
    // i.e. lanes 0..31 = step 2p features, lanes 32..63 = step 2p+1 features.
    const float* xb = x + (size_t)b * T * 32;
    const int xmax = T * 32 - 1;
    float xv0 = xb[min(lane, xmax)];            // pair 0
    float xv1 = xb[min(64 + lane, xmax)];       // pair 1

    float h = 0.0f, c = 0.0f, hsum = 0.0f;
    const int fullpairs = L >> 1;
    for (int p = 0; p < fullpairs; ++p) {
        const float xvn = xb[min((p + 2) * 64 + lane, xmax)];  // prefetch pair p+2
        lstm_step(xv0, 0, wiA, whA, wiB, whB, bA, bB, h, c, hsum);
        lstm_step(xv0, 1, wiA, whA, wiB, whB, bA, bB, h, c, hsum);
        xv0 = xv1; xv1 = xvn;
    }
    if (L & 1)
        lstm_step(xv0, 0, wiA, whA, wiB, whB, bA, bB, h, c, hsum);

    // ---- masked mean pool ----
    const float pooled = hsum / Lf;
    if (lane < 32) out[(size_t)b * 32 + lane] = pooled;

    // ---- classifier ----
    float contrib = (lane < 32) ? pooled * w_cls[lane] : 0.0f;
#pragma unroll
    for (int off = 32; off > 0; off >>= 1) contrib += __shfl_down(contrib, off, 64);
    if (lane == 0)
        out[(size_t)B * 32 + b] = fast_sigmoid(contrib + b_cls[0]);
}

extern "C" void kernel_launch(void* const* d_in, const int* in_sizes, int n_in,
                              void* d_out, int out_size, void* d_ws, size_t ws_size,
                              hipStream_t stream)
{
    const float* x     = (const float*)d_in[0];
    const float* mask  = (const float*)d_in[1];
    const float* w_ih  = (const float*)d_in[2];
    const float* w_hh  = (const float*)d_in[3];
    const float* b_ih  = (const float*)d_in[4];
    const float* b_hh  = (const float*)d_in[5];
    const float* w_cls = (const float*)d_in[6];
    const float* b_cls = (const float*)d_in[7];
    float* out = (float*)d_out;

    const int B = out_size / 33;        // pooled B*32 + probs B
    const int T = in_sizes[1] / B;      // mask is [B,T]

    lstm_fused_kernel<<<B, 64, 0, stream>>>(x, mask, w_ih, w_hh, b_ih, b_hh,
                                            w_cls, b_cls, out, B, T);
}

// Round 3
// 922.566 us; speedup vs baseline: 1.6672x; 1.0438x over previous
//
#include <hip/hip_runtime.h>

// LSTM (H=32), B=2048, T=1024, prefix-masked + mean pool + sigmoid classifier.
// 3 kernels: (1) lengths from mask, (2) one-block counting sort of batch
// indices by length, (3) main LSTM: 1024 waves, wave p runs sorted[p] then
// sorted[B-1-p] sequentially => every wave does ~L_min+L_max ~= T+1 steps
// (scheduler-independent load balance). Weights live in 128 *named* VGPRs
// (macro-expanded, SROA-proof). x-part of the matvec is software-pipelined
// one step ahead (independent of h) to hide the gate-chain latency.

__device__ __forceinline__ float fast_sigmoid(float x) {
    return __builtin_amdgcn_rcpf(1.0f + __expf(-x));
}
__device__ __forceinline__ float fast_tanh(float x) {
    return fmaf(2.0f, fast_sigmoid(2.0f * x), -1.0f);
}
__device__ __forceinline__ float lane_bcast(float v, int srclane) {
    return __int_as_float(__builtin_amdgcn_readlane(__float_as_int(v), srclane));
}

// ---- macro machinery: 128 named weight registers ----
#define R16A(M) M(0) M(1) M(2) M(3) M(4) M(5) M(6) M(7) \
                M(8) M(9) M(10) M(11) M(12) M(13) M(14) M(15)
#define R16B(M) M(16) M(17) M(18) M(19) M(20) M(21) M(22) M(23) \
                M(24) M(25) M(26) M(27) M(28) M(29) M(30) M(31)
#define R32(M) R16A(M) R16B(M)

#define DECLW(i) float wiA_##i, whA_##i, wiB_##i, whB_##i;
#define LOADW(i) wiA_##i = w_ih[rA32 + (i)]; whA_##i = w_hh[rA32 + (i)]; \
                 wiB_##i = w_ih[rB32 + (i)]; whB_##i = w_hh[rB32 + (i)];

// x-part FMAs (uses register `xq`, accumulators ax{A,B}{0,1}n)
#define XP0(i) { const float xm = lane_bcast(xq, i); \
                 axA0n = fmaf(xm, wiA_##i, axA0n); axB0n = fmaf(xm, wiB_##i, axB0n); }
#define XP1(i) { const float xm = lane_bcast(xq, i); \
                 axA1n = fmaf(xm, wiA_##i, axA1n); axB1n = fmaf(xm, wiB_##i, axB1n); }
// h-part FMAs (uses register `h`, accumulators ah{A,B}{0,1})
#define HP0(i) { const float hm = lane_bcast(h, i); \
                 ahA0 = fmaf(hm, whA_##i, ahA0); ahB0 = fmaf(hm, whB_##i, ahB0); }
#define HP1(i) { const float hm = lane_bcast(h, i); \
                 ahA1 = fmaf(hm, whA_##i, ahA1); ahB1 = fmaf(hm, whB_##i, ahB1); }

// ---- kernel 1: sequence lengths from prefix mask ----
__global__ __launch_bounds__(64)
void len_kernel(const float* __restrict__ mask, int* __restrict__ lens, int B, int T)
{
    const int b = blockIdx.x;
    if (b >= B) return;
    const int lane = threadIdx.x;
    const float4* m4 = (const float4*)(mask + (size_t)b * T);
    float s = 0.0f;
    for (int i = lane; i < (T >> 2); i += 64) {
        const float4 v = m4[i];
        s += (v.x + v.y) + (v.z + v.w);
    }
#pragma unroll
    for (int off = 32; off > 0; off >>= 1) s += __shfl_down(s, off, 64);
    if (lane == 0) lens[b] = (int)(s + 0.5f);
}

// ---- kernel 2: one-block counting sort (ascending length) ----
__global__ __launch_bounds__(1024)
void sort_kernel(const int* __restrict__ lens, int* __restrict__ sortedIdx, int B, int T)
{
    __shared__ int hist[1024];
    __shared__ int scan[1024];
    __shared__ int cur[1024];
    const int tid = threadIdx.x;
    if (tid < T) hist[tid] = 0;
    __syncthreads();
    for (int b = tid; b < B; b += blockDim.x)
        atomicAdd(&hist[lens[b] - 1], 1);
    __syncthreads();
    if (tid < T) scan[tid] = hist[tid];
    __syncthreads();
    for (int off = 1; off < T; off <<= 1) {          // Hillis-Steele inclusive
        int v = 0;
        if (tid >= off && tid < T) v = scan[tid - off];
        __syncthreads();
        if (tid < T) scan[tid] += v;
        __syncthreads();
    }
    if (tid < T) cur[tid] = scan[tid] - hist[tid];   // exclusive prefix
    __syncthreads();
    for (int b = tid; b < B; b += blockDim.x) {
        const int pos = atomicAdd(&cur[lens[b] - 1], 1);
        sortedIdx[pos] = b;
    }
}

// ---- kernel 3: main LSTM, 1 wave per complement-pair of sequences ----
__global__ __launch_bounds__(64, 2)
void lstm_main(const float* __restrict__ x,        // [B,T,32]
               const int* __restrict__ lens,       // [B]
               const int* __restrict__ sortedIdx,  // [B]
               const float* __restrict__ w_ih,     // [128,32]
               const float* __restrict__ w_hh,     // [128,32]
               const float* __restrict__ b_ih,     // [128]
               const float* __restrict__ b_hh,     // [128]
               const float* __restrict__ w_cls,    // [1,32]
               const float* __restrict__ b_cls,    // [1]
               float* __restrict__ out,            // pooled [B,32] ++ probs [B]
               int B, int T)
{
    const int p = blockIdx.x;                      // 0 .. B/2-1
    const int lane = threadIdx.x;
    const int lm = lane & 31;
    const int rA32 = lane * 32;                    // rows 0..63  : i / f
    const int rB32 = (lane + 64) * 32;             // rows 64..127: g / o
    const int Tm1 = T - 1;

    R32(DECLW)
    R32(LOADW)
    const float bA = b_ih[lane] + b_hh[lane];
    const float bB = b_ih[lane + 64] + b_hh[lane + 64];

    for (int s = 0; s < 2; ++s) {
        const int b = sortedIdx[s == 0 ? p : (B - 1 - p)];
        const int L = lens[b];
        const float* xb = x + (size_t)b * T * 32;

        float h = 0.0f, c = 0.0f, hsum = 0.0f;

        // prime: x-part of step 0
        float xq = xb[lm];                                     // x_0
        float axA0n = bA, axA1n = 0.f, axB0n = bB, axB1n = 0.f;
        R16A(XP0) R16B(XP1)
        float axA0c = axA0n, axA1c = axA1n, axB0c = axB0n, axB1c = axB1n;
        xq = xb[min(1, Tm1) * 32 + lm];                        // x_1

        for (int t = 0; t < L; ++t) {
            const float xn = xb[min(t + 2, Tm1) * 32 + lm];    // prefetch x_{t+2}
            // h-part of step t
            float ahA0 = 0.f, ahA1 = 0.f, ahB0 = 0.f, ahB1 = 0.f;
            R16A(HP0) R16B(HP1)
            const float accA = (axA0c + ahA0) + (axA1c + ahA1);  // i / f preact
            const float accB = (axB0c + ahB0) + (axB1c + ahB1);  // g / o preact
            const float accA2 = __shfl_xor(accA, 32, 64);
            const float accB2 = __shfl_xor(accB, 32, 64);
            const float ig = fast_sigmoid(accA);
            const float fg = fast_sigmoid(accA2);
            const float gg = fast_tanh(accB);
            const float og = fast_sigmoid(accB2);
            c = fg * c + ig * gg;        // lanes >=32: bounded garbage, never read
            h = og * fast_tanh(c);
            hsum += h;
            // x-part of step t+1 (independent of h-chain -> fills gate latency)
            axA0n = bA; axA1n = 0.f; axB0n = bB; axB1n = 0.f;
            R16A(XP0) R16B(XP1)
            axA0c = axA0n; axA1c = axA1n; axB0c = axB0n; axB1c = axB1n;
            xq = xn;
        }

        const float Lf = (float)L;                 // L >= 1 always
        const float pooled = hsum / Lf;
        if (lane < 32) out[(size_t)b * 32 + lane] = pooled;

        float contrib = (lane < 32) ? pooled * w_cls[lane] : 0.0f;
#pragma unroll
        for (int off = 32; off > 0; off >>= 1)
            contrib += __shfl_down(contrib, off, 64);
        if (lane == 0)
            out[(size_t)B * 32 + b] = fast_sigmoid(contrib + b_cls[0]);
    }
}

extern "C" void kernel_launch(void* const* d_in, const int* in_sizes, int n_in,
                              void* d_out, int out_size, void* d_ws, size_t ws_size,
                              hipStream_t stream)
{
    const float* x     = (const float*)d_in[0];
    const float* mask  = (const float*)d_in[1];
    const float* w_ih  = (const float*)d_in[2];
    const float* w_hh  = (const float*)d_in[3];
    const float* b_ih  = (const float*)d_in[4];
    const float* b_hh  = (const float*)d_in[5];
    const float* w_cls = (const float*)d_in[6];
    const float* b_cls = (const float*)d_in[7];
    float* out = (float*)d_out;

    const int B = out_size / 33;        // pooled B*32 + probs B
    const int T = in_sizes[1] / B;      // mask is [B,T]

    int* lens = (int*)d_ws;
    int* sidx = lens + B;

    len_kernel<<<B, 64, 0, stream>>>(mask, lens, B, T);
    sort_kernel<<<1, 1024, 0, stream>>>(lens, sidx, B, T);
    lstm_main<<<B / 2, 64, 0, stream>>>(x, lens, sidx, w_ih, w_hh, b_ih, b_hh,
                                        w_cls, b_cls, out, B, T);
}